// Round 6
// baseline (43.889 us; speedup 1.0000x reference)
//
#include <hip/hip_runtime.h>

// Bilateral-grid slicing, v4: 4-row blocks, y-pre-lerped LDS, 8px/thread.
//   grid : (B=16, C=12, D=8, H=16, W=16) f32
//   guide: (B=16, 1, 512, 512) f32
//   out  : (B=16, C=12, 512, 512) f32
//
// Block = 256 threads = 4 rows of one batch (8 consecutive px per thread).
// Rows 4k..4k+3 share y0 (transitions at h=32n+16, multiple of 4), so the
// block stages 2 raw y-slices once and pre-lerps y per row:
//   L[row][c][x][z] = G[y0]*(1-fy_r) + G[y0+1]*fy_r
// dword idx = row*1728 + c*144 + x*9 + z  (27 KB).
// Per pixel-channel: bilinear (x,z) = 2 ds_read2_b32 + 3 lerps.

typedef float vfloat4 __attribute__((ext_vector_type(4)));

constexpr int C = 12, D = 8, H = 16, W = 16, GH = 512, GW = 512;
constexpr int XST  = 9;            // x stride in LDS dwords (8 z + 1 pad)
constexpr int CSTR = 16 * XST;     // per-channel stride = 144
constexpr int RST  = C * CSTR;     // per-row stride = 1728
constexpr int LDS_FLOATS = 4 * RST; // 6912 dwords = 27 KB

__global__ void slice_kernel(const float* __restrict__ grid,
                             const float* __restrict__ guide,
                             float* __restrict__ out)
{
    __shared__ float S[LDS_FLOATS];
    const int t   = threadIdx.x;
    const int bid = blockIdx.x;
    const int b   = bid >> 7;            // 128 blocks per batch
    const int h0  = (bid & 127) << 2;    // 4 rows per block

    // shared y cell + per-row weights
    float iyr0 = fminf(fmaxf((float)h0 * 0.03125f - 0.5f, 0.0f), 15.0f);
    const int y0 = min((int)iyr0, H - 2);      // [0,14]
    float fyr[4];
#pragma unroll
    for (int r = 0; r < 4; ++r) {
        float iyr = fminf(fmaxf((float)(h0 + r) * 0.03125f - 0.5f, 0.0f), 15.0f);
        fyr[r] = iyr - (float)y0;              // [0,1]
    }

    // this thread's 8-pixel span
    const int row = t >> 6;
    const int w0  = (t & 63) << 3;
    const int h   = h0 + row;

    // hoist guide loads (independent of staging)
    const float* gp = guide + (((b << 9) + h) << 9) + w0;
    const vfloat4 gA = *reinterpret_cast<const vfloat4*>(gp);
    const vfloat4 gB = *reinterpret_cast<const vfloat4*>(gp + 4);

    // ---- stage: 384 chunk-pairs -> 4 pre-lerped row slices ----
    const float* gb = grid + (size_t)b * (C * D * H * W);
#pragma unroll
    for (int iter = 0; iter < 2; ++iter) {
        int i = t + (iter << 8);
        if (i < 384) {
            int x4 = i & 3;              // float4 chunk within 16-x row
            int z  = (i >> 2) & 7;
            int c  = i >> 5;
            const float* p0 = gb + ((c * D + z) * H + y0) * W + (x4 << 2);
            const vfloat4 v0 = *reinterpret_cast<const vfloat4*>(p0);
            const vfloat4 v1 = *reinterpret_cast<const vfloat4*>(p0 + W);
            const vfloat4 dv = v1 - v0;
            int x0 = x4 << 2;
            int dbase = c * CSTR + z;
#pragma unroll
            for (int r = 0; r < 4; ++r) {
                const vfloat4 vr = v0 + fyr[r] * dv;
                int d = dbase + r * RST;
                S[d + (x0 + 0) * XST] = vr.x;
                S[d + (x0 + 1) * XST] = vr.y;
                S[d + (x0 + 2) * XST] = vr.z;
                S[d + (x0 + 3) * XST] = vr.w;
            }
        }
    }
    __syncthreads();

    // ---- per-pixel x/z setup (8 px) ----
    const float gz[8] = {gA.x, gA.y, gA.z, gA.w, gB.x, gB.y, gB.z, gB.w};
    int   pb[8];
    float fzv[8], wx0[8], wx1[8];
#pragma unroll
    for (int j = 0; j < 8; ++j) {
        float ix = fminf(fmaxf((float)(w0 + j) * 0.03125f - 0.5f, 0.0f), 15.0f);
        int   x0c = min((int)ix, W - 2);
        float fx  = ix - (float)x0c;

        float iz = fminf(fmaxf(gz[j] * 4.0f + 3.5f, 0.0f), 7.0f);
        int   z0c = min((int)iz, D - 2);
        fzv[j] = iz - (float)z0c;

        pb[j]  = row * RST + x0c * XST + z0c;
        wx1[j] = fx;
        wx0[j] = 1.0f - fx;
    }

    const size_t obase = (((size_t)b * C) * GH + h) * GW + w0;
#pragma unroll
    for (int c = 0; c < C; ++c) {
        float acc[8];
#pragma unroll
        for (int j = 0; j < 8; ++j) {
            const int base = c * CSTR + pb[j];
            float a0 = S[base],       a1 = S[base + 1];
            float b0 = S[base + XST], b1 = S[base + XST + 1];
            float f  = fzv[j];
            float va = a0 + f * (a1 - a0);
            float vb = b0 + f * (b1 - b0);
            acc[j] = wx0[j] * va + wx1[j] * vb;
        }
        float* op = out + obase + (size_t)c * (GH * GW);
        vfloat4 r0, r1;
        r0.x = acc[0]; r0.y = acc[1]; r0.z = acc[2]; r0.w = acc[3];
        r1.x = acc[4]; r1.y = acc[5]; r1.z = acc[6]; r1.w = acc[7];
        *reinterpret_cast<vfloat4*>(op)     = r0;
        *reinterpret_cast<vfloat4*>(op + 4) = r1;
    }
}

extern "C" void kernel_launch(void* const* d_in, const int* in_sizes, int n_in,
                              void* d_out, int out_size, void* d_ws, size_t ws_size,
                              hipStream_t stream) {
    const float* grid  = (const float*)d_in[0];
    const float* guide = (const float*)d_in[1];
    float* out = (float*)d_out;
    (void)in_sizes; (void)n_in; (void)out_size; (void)d_ws; (void)ws_size;

    dim3 block(256);
    dim3 gridDim(2048);   // 16 batches * 128 four-row groups
    hipLaunchKernelGGL(slice_kernel, gridDim, block, 0, stream, grid, guide, out);
}

// Round 7
// 40.586 us; speedup vs baseline: 1.0814x; 1.0814x over previous
//
#include <hip/hip_runtime.h>

// Bilateral-grid slicing, v5: channel-innermost (v,dz) LDS pairs.
//   grid : (B=16, C=12, D=8, H=16, W=16) f32
//   guide: (B=16, 1, 512, 512) f32
//   out  : (B=16, C=12, 512, 512) f32
//
// Block = 256 threads = 2 rows of one batch (1 quad of 4 px per thread).
// Rows share y0; staging pre-lerps y per row AND pre-computes z-deltas:
//   S[row][x][z][c] = { v, v(z+1)-v(z) }   (pairs, c innermost)
// dword idx = row*2800 + x*175 + z*25 + 2c   (21.9 KB)
// Per pixel-channel: 2 ds_read2_b32 (imm offsets 2c/2c+1, 175+2c/176+2c
// from ONE per-pixel base VGPR) + 5 VALU:
//   va=fma(fz,d0,a0); vb=fma(fz,d1,b0); acc=va+fx*(vb-va)

typedef float vfloat4 __attribute__((ext_vector_type(4)));

constexpr int C = 12, D = 8, H = 16, W = 16, GH = 512, GW = 512;
constexpr int ZST  = 25;             // per-z stride in dwords (24 used + 1 pad)
constexpr int XSTR = 7 * ZST;        // 175 (z-cells 0..6 hold (v,d) pairs)
constexpr int RSTR = 16 * XSTR;      // 2800 per row-slice
constexpr int LDS_FLOATS = 2 * RSTR; // 5600 dwords = 21.9 KB

__global__ void slice_kernel(const float* __restrict__ grid,
                             const float* __restrict__ guide,
                             float* __restrict__ out)
{
    __shared__ float S[LDS_FLOATS];
    const int t   = threadIdx.x;
    const int bid = blockIdx.x;
    const int b   = bid >> 8;            // 256 blocks per batch
    const int h0  = (bid & 255) << 1;    // 2 rows per block

    // rows h0, h0+1 share y0; per-row fractional weights
    float iyr0 = fminf(fmaxf((float)h0       * 0.03125f - 0.5f, 0.0f), 15.0f);
    float iyr1 = fminf(fmaxf((float)(h0 + 1) * 0.03125f - 0.5f, 0.0f), 15.0f);
    const int   y0  = min((int)iyr0, H - 2);   // [0,14]
    const float fy0 = iyr0 - (float)y0;
    const float fy1 = iyr1 - (float)y0;

    // this thread's quad (threads 0-127 -> row 0, 128-255 -> row 1)
    const int row = t >> 7;
    const int w0  = (t & 127) << 2;
    const int h   = h0 + row;

    // hoist guide load (independent of staging)
    const vfloat4 g4 = *reinterpret_cast<const vfloat4*>(
        guide + (((b << 9) + h) << 9) + w0);

    // ---- stage: chunks (x4, z in 0..6, c) -> (v, dz) pairs, y-pre-lerped ----
    const float* gb = grid + (size_t)b * (C * D * H * W);
#pragma unroll
    for (int iter = 0; iter < 2; ++iter) {
        int i = t + (iter << 8);
        if (i < 384) {
            int x4 = i & 3;              // float4 chunk within 16-x row
            int z  = (i >> 2) & 7;
            int c  = i >> 5;             // < 12
            if (z < 7) {
                const float* p = gb + ((c * D + z) * H + y0) * W + (x4 << 2);
                const vfloat4 v00 = *reinterpret_cast<const vfloat4*>(p);            // (z,  y0)
                const vfloat4 v10 = *reinterpret_cast<const vfloat4*>(p + W);        // (z,  y0+1)
                const vfloat4 v01 = *reinterpret_cast<const vfloat4*>(p + H * W);    // (z+1,y0)
                const vfloat4 v11 = *reinterpret_cast<const vfloat4*>(p + H * W + W);// (z+1,y0+1)
                const vfloat4 dy0 = v10 - v00;
                const vfloat4 dy1 = v11 - v01;
                const vfloat4 r0a = v00 + fy0 * dy0;   // row0, z
                const vfloat4 r0b = v01 + fy0 * dy1;   // row0, z+1
                const vfloat4 d0  = r0b - r0a;
                const vfloat4 r1a = v00 + fy1 * dy0;   // row1, z
                const vfloat4 r1b = v01 + fy1 * dy1;
                const vfloat4 d1  = r1b - r1a;
                const int x0 = x4 << 2;
                const int e0 = x0 * XSTR + z * ZST + 2 * c;
#pragma unroll
                for (int k = 0; k < 4; ++k) {
                    int e = e0 + k * XSTR;
                    S[e]            = r0a[k];
                    S[e + 1]        = d0[k];
                    S[e + RSTR]     = r1a[k];
                    S[e + RSTR + 1] = d1[k];
                }
            }
        }
    }
    __syncthreads();

    // ---- per-pixel x/z setup ----
    const float gz[4] = {g4.x, g4.y, g4.z, g4.w};
    int   pbv[4];
    float fzv[4], fxv[4];
#pragma unroll
    for (int j = 0; j < 4; ++j) {
        float ix = fminf(fmaxf((float)(w0 + j) * 0.03125f - 0.5f, 0.0f), 15.0f);
        int   x0c = min((int)ix, W - 2);
        fxv[j] = ix - (float)x0c;

        float iz = fminf(fmaxf(gz[j] * 4.0f + 3.5f, 0.0f), 7.0f);
        int   z0c = min((int)iz, D - 2);
        fzv[j] = iz - (float)z0c;

        pbv[j] = row * RSTR + x0c * XSTR + z0c * ZST;
    }

    const size_t obase = (((size_t)b * C) * GH + h) * GW + w0;
#pragma unroll
    for (int c = 0; c < C; ++c) {
        float acc[4];
#pragma unroll
        for (int j = 0; j < 4; ++j) {
            const int ba = pbv[j] + 2 * c;
            float a0 = S[ba],        ad = S[ba + 1];
            float b0 = S[ba + XSTR], bd = S[ba + XSTR + 1];
            float va = fmaf(fzv[j], ad, a0);
            float vb = fmaf(fzv[j], bd, b0);
            acc[j] = va + fxv[j] * (vb - va);
        }
        vfloat4 r;
        r.x = acc[0]; r.y = acc[1]; r.z = acc[2]; r.w = acc[3];
        *reinterpret_cast<vfloat4*>(out + obase + (size_t)c * (GH * GW)) = r;
    }
}

extern "C" void kernel_launch(void* const* d_in, const int* in_sizes, int n_in,
                              void* d_out, int out_size, void* d_ws, size_t ws_size,
                              hipStream_t stream) {
    const float* grid  = (const float*)d_in[0];
    const float* guide = (const float*)d_in[1];
    float* out = (float*)d_out;
    (void)in_sizes; (void)n_in; (void)out_size; (void)d_ws; (void)ws_size;

    dim3 block(256);
    dim3 gridDim(4096);   // 16 batches * 256 two-row groups
    hipLaunchKernelGGL(slice_kernel, gridDim, block, 0, stream, grid, guide, out);
}